// Round 6
// baseline (302.931 us; speedup 1.0000x reference)
//
#include <hip/hip_runtime.h>
#include <hip/hip_bf16.h>

// Problem constants
#define BATCH 4
#define SEQ   2048
#define DM    1024
#define NH    16
#define DEPTH 64
#define ROWS  (BATCH*SEQ)   // 8192
#define NQKV  (3*DM)        // 3072
#define BH    (BATCH*NH)    // 64

typedef __attribute__((ext_vector_type(8))) short bf16x8;
typedef __attribute__((ext_vector_type(4))) float f32x4;
typedef __attribute__((ext_vector_type(16))) float f32x16;
typedef unsigned short u16;
typedef unsigned int   u32;

__device__ __forceinline__ u16 f2bf(float f) {
    union { float f; unsigned u; } v; v.f = f;
    unsigned r = v.u + 0x7fff + ((v.u >> 16) & 1);   // RNE
    return (u16)(r >> 16);
}

__device__ __forceinline__ u32 pk2bf(float a, float b) {
#if __has_builtin(__builtin_amdgcn_cvt_pk_bf16_f32)
    typedef __attribute__((ext_vector_type(2))) __bf16 v2bf;
    union { v2bf v; u32 u; } u_;
    u_.v = __builtin_amdgcn_cvt_pk_bf16_f32(a, b);
    return u_.u;
#else
    return (u32)f2bf(a) | ((u32)f2bf(b) << 16);
#endif
}

// exchange: x' = [x_lo | y_lo], y' = [x_hi | y_hi]  (32-lane halves)
__device__ __forceinline__ void pl32swap(u32& x, u32& y) {
#if __has_builtin(__builtin_amdgcn_permlane32_swap)
    typedef __attribute__((ext_vector_type(2))) int v2i;
    v2i r = __builtin_amdgcn_permlane32_swap((int)x, (int)y, false, false);
    x = (u32)r[0]; y = (u32)r[1];
#else
    u32 sx = (u32)__shfl_xor((int)x, 32);
    u32 sy = (u32)__shfl_xor((int)y, 32);
    bool hi = (threadIdx.x & 32) != 0;
    u32 nx = hi ? sy : x;
    u32 ny = hi ? y : sx;
    x = nx; y = ny;
#endif
}

__device__ __forceinline__ bf16x8 pack4(u32 a, u32 b, u32 c, u32 d) {
    union { u32 u[4]; bf16x8 v; } x;
    x.u[0] = a; x.u[1] = b; x.u[2] = c; x.u[3] = d;
    return x.v;
}

// async global->LDS, 16B per lane. LDS dest must be wave-uniform base + lane*16.
__device__ __forceinline__ void g2l16(void* lds, const void* g) {
    __builtin_amdgcn_global_load_lds((const __attribute__((address_space(1))) void*)g,
                                     (__attribute__((address_space(3))) void*)lds, 16, 0, 0);
}

// read one 16B MFMA fragment from an unpadded [rows][64] tile with XOR-granule swizzle:
// logical granule gl (8 elems) of row r lives at physical granule gl ^ (r&7).
__device__ __forceinline__ bf16x8 frag8(const u16* tile, int row, int gl) {
    return *(const bf16x8*)(tile + row * 64 + ((gl ^ (row & 7)) * 8));
}

__device__ __forceinline__ f32x16 mfma32(bf16x8 a, bf16x8 b, f32x16 c) {
    return __builtin_amdgcn_mfma_f32_32x32x16_bf16(a, b, c, 0, 0, 0);
}

// ---------------- fused prep: x->bf16 + LDS-tiled weight transposes ----------------
__global__ __launch_bounds__(256) void k_prep(const float* __restrict__ x,
                                              const float* __restrict__ Wq, const float* __restrict__ Wk,
                                              const float* __restrict__ Wv, const float* __restrict__ Wo,
                                              u16* __restrict__ xb, u16* __restrict__ BT, u16* __restrict__ WoT) {
    __shared__ u16 T[64][65];
    int tid = threadIdx.x;
    int bx = blockIdx.x;
    if (bx < 2048) {
        int i = bx * 4096 + tid * 4;
        for (int l = 0; l < 4; ++l) {
            float4 v = *(const float4*)(x + i + l * 1024);
            ushort4 o; o.x = f2bf(v.x); o.y = f2bf(v.y); o.z = f2bf(v.z); o.w = f2bf(v.w);
            *(ushort4*)(xb + i + l * 1024) = o;
        }
        return;
    }
    if (bx < 2816) {
        int q = bx - 2048;
        int kt = q & 15, mh = q >> 4, m = mh >> 4, h = mh & 15;
        const float* W = (m == 0) ? Wq : (m == 1) ? Wk : Wv;
        const float* src = W + ((size_t)h * 1024 + kt * 64) * 64;   // src[r][e], stride 64
        int e = tid & 63, r0 = tid >> 6;
        for (int i = 0; i < 16; ++i) { int r = i * 4 + r0; T[r][e] = f2bf(src[r * 64 + e]); }
        __syncthreads();
        int kk = tid & 63, e0 = tid >> 6;
        u16* dst = BT + ((size_t)m * 1024 + h * 64) * 1024 + kt * 64;  // [e-row][k-col]
        for (int i = 0; i < 16; ++i) { int ee = i * 4 + e0; dst[ee * 1024 + kk] = T[kk][ee]; }
        return;
    }
    {
        int q = bx - 2816;
        int kt = q & 15, nt = q >> 4;
        const float* src = Wo + (size_t)kt * 64 * 1024 + nt * 64;   // src[r][c], stride 1024
        int c = tid & 63, r0 = tid >> 6;
        for (int i = 0; i < 16; ++i) { int r = i * 4 + r0; T[r][c] = f2bf(src[r * 1024 + c]); }
        __syncthreads();
        int kk = tid & 63, e0 = tid >> 6;
        u16* dst = WoT + (size_t)nt * 64 * 1024 + kt * 64;
        for (int i = 0; i < 16; ++i) { int ee = i * 4 + e0; dst[ee * 1024 + kk] = T[kk][ee]; }
    }
}

// ---------------- merged QKV projection GEMMs ----------------
// blocks [0,1024): C = xb @ Wqkv[:,0:2048] -> Q (scaled), K    (16 col-tiles x 64 row-tiles)
// blocks [1024,1536): C = Wv_rows @ xb^T -> VT                 (64 col-tiles x 8 row-tiles)
__global__ __launch_bounds__(256) void k_gemm_qkv(const u16* __restrict__ xb, const u16* __restrict__ Wt,
                                                  const float* __restrict__ bq, const float* __restrict__ bk,
                                                  const float* __restrict__ bv,
                                                  u16* __restrict__ Q, u16* __restrict__ K, u16* __restrict__ VT) {
    __shared__ u16 Al[128 * 64];
    __shared__ u16 Bl[128 * 64];
    int tid = threadIdx.x;
    int wave = tid >> 6, lane = tid & 63, ln = lane & 15, quad = lane >> 4;
    int b = blockIdx.x;
    bool isvt = (b >= 1024);
    int row0, col0;
    const u16 *Am, *Bm;
    if (!isvt) {
        col0 = (b & 15) * 128; row0 = (b >> 4) * 128;
        Am = xb + (size_t)row0 * 1024; Bm = Wt + (size_t)col0 * 1024;
    } else {
        int b2 = b - 1024;
        col0 = (b2 & 63) * 128; row0 = (b2 >> 6) * 128;
        Am = Wt + (size_t)2048 * 1024 + (size_t)row0 * 1024; Bm = xb + (size_t)col0 * 1024;
    }
    int moff = (wave >> 1) * 64, noff = (wave & 1) * 64;
    f32x4 acc[4][4] = {};

    for (int k0 = 0; k0 < 1024; k0 += 64) {
        for (int l = 0; l < 4; ++l) {
            int idx = tid + l * 256, r = idx >> 3, gs = ((idx & 7) ^ (r & 7)) * 8;
            g2l16(&Al[idx * 8], Am + r * 1024 + k0 + gs);
            g2l16(&Bl[idx * 8], Bm + r * 1024 + k0 + gs);
        }
        __syncthreads();
        for (int kk = 0; kk < 2; ++kk) {
            bf16x8 a[4], bb[4];
            for (int i = 0; i < 4; ++i) a[i]  = frag8(Al, moff + i * 16 + ln, kk * 4 + quad);
            for (int j = 0; j < 4; ++j) bb[j] = frag8(Bl, noff + j * 16 + ln, kk * 4 + quad);
            for (int i = 0; i < 4; ++i)
                for (int j = 0; j < 4; ++j)
                    acc[i][j] = __builtin_amdgcn_mfma_f32_16x16x32_bf16(a[i], bb[j], acc[i][j], 0, 0, 0);
        }
        __syncthreads();
    }

    if (!isvt) {
        // Q scale folds 1/sqrt(64) AND log2(e) so attention uses exp2 directly.
        const float QSCALE = 0.125f * 1.4426950408889634f;
        for (int j = 0; j < 4; ++j) {
            int c = col0 + noff + j * 16 + ln;
            int m = c >> 10, h = (c >> 6) & 15, e = c & 63;
            const float* bias = (m == 0) ? bq : bk;
            float bval = bias[h * 64 + e];
            for (int i = 0; i < 4; ++i)
                for (int r = 0; r < 4; ++r) {
                    int rowg = row0 + moff + i * 16 + quad * 4 + r;
                    int b_ = rowg >> 11, s = rowg & 2047;
                    int bh = b_ * 16 + h;
                    float v = acc[i][j][r] + bval;
                    if (m == 0) Q[(bh * 2048 + s) * 64 + e] = f2bf(v * QSCALE);
                    else        K[(bh * 2048 + s) * 64 + e] = f2bf(v);
                }
        }
    } else {
        for (int j = 0; j < 4; ++j) {
            int c = col0 + noff + j * 16 + ln;
            int b_ = c >> 11, s = c & 2047;
            for (int i = 0; i < 4; ++i)
                for (int r = 0; r < 4; ++r) {
                    int ii = row0 + moff + i * 16 + quad * 4 + r;     // = h*64+e
                    float v = acc[i][j][r] + bv[ii];
                    VT[((size_t)b_ * 1024 + ii) * 2048 + s] = f2bf(v);
                }
        }
    }
}

// ---------------- flash attention: 32x32x16, register-resident P via permlane32_swap ----
// grid (8, 64), block 256 (4 waves). Wave w owns queries [bx*256 + w*64, +64) as qt in {0,1}.
// Scores S^T = mfma(A=kf, B=qb): C-layout col=lane&31=query, row=key=(reg&3)+8(reg>>2)+4h.
// exp2 -> packed bf16 pairs g0..g7 (per kt,qt). permlane32_swap pairs convert C-layout
// directly to the PV A-operand layout (m=query=lane&31, k=key=8h+i). No P LDS round-trip.
// K,Q frags direct from global (L1/L2 pipe); only V staged in LDS (ping-pong, 1 barrier/tile).
// O = mfma(A=P, B=vf) C-layout: col=d, row=query -> normalize via linv LDS redistribute.
__global__ __launch_bounds__(256, 2) void k_attn(const u16* __restrict__ Q, const u16* __restrict__ K,
                                                 const u16* __restrict__ VT, u16* __restrict__ A2) {
    __shared__ u16 Vl[2][64 * 64];
    __shared__ float linv[256];
    int tid = threadIdx.x;
    int w = tid >> 6, lane = tid & 63, l31 = lane & 31, h = lane >> 5;
    int bh = blockIdx.y;
    int m0 = blockIdx.x * 256;
    const u16* Qb = Q + (size_t)bh * 2048 * 64;
    const u16* Kb = K + (size_t)bh * 2048 * 64;
    const u16* Vb = VT + (size_t)bh * 64 * 2048;

    // V staging: 2 rounds x 256 threads x 16B = one 64x64 tile (XOR-swizzled granules)
    int sidx[2]; const u16* vsrc[2];
    for (int rr = 0; rr < 2; ++rr) {
        int idx = tid + rr * 256, r = idx >> 3, g = (idx & 7) ^ (r & 7);
        sidx[rr] = idx * 8;
        vsrc[rr] = Vb + r * 2048 + g * 8;
    }
    g2l16(&Vl[0][sidx[0]], vsrc[0]);
    g2l16(&Vl[0][sidx[1]], vsrc[1]);

    // Q fragments direct from global: B-operand, n=query=l31, k(d) = s*16 + 8h + i
    bf16x8 qb[2][4];
    for (int qt = 0; qt < 2; ++qt)
        for (int s = 0; s < 4; ++s)
            qb[qt][s] = *(const bf16x8*)(Qb + (m0 + w * 64 + qt * 32 + l31) * 64 + s * 16 + h * 8);
    __syncthreads();

    f32x16 oacc[2][2] = {};          // [qt][dt], C-layout rows=query, cols=d
    float lsum[2] = {0.f, 0.f};

    for (int t = 0; t < 32; ++t) {
        // K fragments direct from global: A-operand, m=key=l31, k(d) = s*16+8h+i
        const u16* Kt = Kb + t * 64 * 64;
        bf16x8 kf[2][4];
        for (int kt = 0; kt < 2; ++kt)
            for (int s = 0; s < 4; ++s)
                kf[kt][s] = *(const bf16x8*)(Kt + (kt * 32 + l31) * 64 + s * 16 + h * 8);

        // V DMA for next tile into the other buffer (full compute window to land)
        if (t < 31) {
            g2l16(&Vl[(t + 1) & 1][sidx[0]], vsrc[0] + (t + 1) * 64);
            g2l16(&Vl[(t + 1) & 1][sidx[1]], vsrc[1] + (t + 1) * 64);
        }
        const u16* vb = Vl[t & 1];

        for (int kt = 0; kt < 2; ++kt) {
            f32x16 sc[2] = {};
            for (int s = 0; s < 4; ++s) {
                sc[0] = mfma32(kf[kt][s], qb[0][s], sc[0]);
                sc[1] = mfma32(kf[kt][s], qb[1][s], sc[1]);
            }
            // V frags for this kt (shared across qt): B-operand, n=d=l31, k=key=8h+i
            bf16x8 vf00 = frag8(vb, l31,      kt * 4 + h);        // dt=0, u=0
            bf16x8 vf01 = frag8(vb, l31,      kt * 4 + 2 + h);    // dt=0, u=1
            bf16x8 vf10 = frag8(vb, 32 + l31, kt * 4 + h);        // dt=1, u=0
            bf16x8 vf11 = frag8(vb, 32 + l31, kt * 4 + 2 + h);    // dt=1, u=1
            for (int qt = 0; qt < 2; ++qt) {
                // exp2 + pack pairs: g covers keys kt*32 + 4h + 8*(g>>1) + 2*(g&1) + {0,1}
                u32 g[8]; float sq = 0.f;
                for (int gi = 0; gi < 8; ++gi) {
                    float p0 = __builtin_amdgcn_exp2f(sc[qt][2 * gi]);
                    float p1 = __builtin_amdgcn_exp2f(sc[qt][2 * gi + 1]);
                    sq += p0 + p1;
                    g[gi] = pk2bf(p0, p1);
                }
                lsum[qt] += sq;
                // C-layout -> A-operand: cross-half swaps
                pl32swap(g[0], g[2]); pl32swap(g[1], g[3]);   // u=0: keys 0..15 of kt tile
                pl32swap(g[4], g[6]); pl32swap(g[5], g[7]);   // u=1: keys 16..31
                bf16x8 a0 = pack4(g[0], g[1], g[2], g[3]);
                bf16x8 a1 = pack4(g[4], g[5], g[6], g[7]);
                oacc[qt][0] = mfma32(a0, vf00, oacc[qt][0]);
                oacc[qt][0] = mfma32(a1, vf01, oacc[qt][0]);
                oacc[qt][1] = mfma32(a0, vf10, oacc[qt][1]);
                oacc[qt][1] = mfma32(a1, vf11, oacc[qt][1]);
            }
        }
        __syncthreads();
    }

    // l: combine halves, park indexed by query, re-read in C-layout rows (wave-private)
    for (int qt = 0; qt < 2; ++qt) {
        float l2 = lsum[qt] + __shfl_xor(lsum[qt], 32);
        linv[w * 64 + qt * 32 + l31] = 1.0f / l2;
    }
    int b_ = bh >> 4, hh = bh & 15;
    for (int qt = 0; qt < 2; ++qt)
        for (int g = 0; g < 4; ++g) {
            f32x4 iv = *(f32x4*)&linv[w * 64 + qt * 32 + 8 * g + 4 * h];
            for (int dt = 0; dt < 2; ++dt)
                for (int r = 0; r < 4; ++r) {
                    int row = b_ * 2048 + m0 + w * 64 + qt * 32 + 8 * g + 4 * h + r;
                    A2[row * 1024 + hh * 64 + dt * 32 + l31] = f2bf(oacc[qt][dt][g * 4 + r] * iv[r]);
                }
        }
}

// ---------------- output projection GEMM ----------------
__global__ __launch_bounds__(256) void k_gemm_out(const u16* __restrict__ A, const u16* __restrict__ BT,
                                                  const float* __restrict__ bo, float* __restrict__ out) {
    __shared__ u16 Al[128 * 64];
    __shared__ u16 Bl[128 * 64];
    int tid = threadIdx.x;
    int wave = tid >> 6, lane = tid & 63, ln = lane & 15, quad = lane >> 4;
    int row0 = blockIdx.y * 128;
    int col0 = blockIdx.x * 128;
    int moff = (wave >> 1) * 64, noff = (wave & 1) * 64;
    f32x4 acc[4][4] = {};

    for (int k0 = 0; k0 < 1024; k0 += 64) {
        for (int l = 0; l < 4; ++l) {
            int idx = tid + l * 256, r = idx >> 3, gs = ((idx & 7) ^ (r & 7)) * 8;
            g2l16(&Al[idx * 8], A  + (row0 + r) * 1024 + k0 + gs);
            g2l16(&Bl[idx * 8], BT + (col0 + r) * 1024 + k0 + gs);
        }
        __syncthreads();
        for (int kk = 0; kk < 2; ++kk) {
            bf16x8 a[4], b[4];
            for (int i = 0; i < 4; ++i) a[i] = frag8(Al, moff + i * 16 + ln, kk * 4 + quad);
            for (int j = 0; j < 4; ++j) b[j] = frag8(Bl, noff + j * 16 + ln, kk * 4 + quad);
            for (int i = 0; i < 4; ++i)
                for (int j = 0; j < 4; ++j)
                    acc[i][j] = __builtin_amdgcn_mfma_f32_16x16x32_bf16(a[i], b[j], acc[i][j], 0, 0, 0);
        }
        __syncthreads();
    }

    for (int j = 0; j < 4; ++j) {
        int c = col0 + noff + j * 16 + ln;
        float bias = bo[c];
        for (int i = 0; i < 4; ++i)
            for (int r = 0; r < 4; ++r) {
                int rowg = row0 + moff + i * 16 + quad * 4 + r;
                out[rowg * 1024 + c] = acc[i][j][r] + bias;
            }
    }
}

extern "C" void kernel_launch(void* const* d_in, const int* in_sizes, int n_in,
                              void* d_out, int out_size, void* d_ws, size_t ws_size,
                              hipStream_t stream) {
    const float* x  = (const float*)d_in[0];
    const float* Wq = (const float*)d_in[1];
    const float* bq = (const float*)d_in[2];
    const float* Wk = (const float*)d_in[3];
    const float* bk = (const float*)d_in[4];
    const float* Wv = (const float*)d_in[5];
    const float* bv = (const float*)d_in[6];
    const float* Wo = (const float*)d_in[7];
    const float* bo = (const float*)d_in[8];
    float* out = (float*)d_out;

    char* ws = (char*)d_ws;
    u16* xb    = (u16*)ws; ws += (size_t)ROWS * DM * 2;        // 16 MB
    u16* WqkvT = (u16*)ws; ws += (size_t)NQKV * DM * 2;        // 6 MB
    u16* WoT   = (u16*)ws; ws += (size_t)DM * DM * 2;          // 2 MB
    u16* Qb    = (u16*)ws; ws += (size_t)BH * SEQ * DEPTH * 2; // 16 MB
    u16* Kb    = (u16*)ws; ws += (size_t)BH * SEQ * DEPTH * 2; // 16 MB
    u16* VTb   = (u16*)ws; ws += (size_t)BH * SEQ * DEPTH * 2; // 16 MB
    u16* A2    = (u16*)ws; ws += (size_t)ROWS * DM * 2;        // 16 MB

    k_prep     <<<dim3(3072),   dim3(256), 0, stream>>>(x, Wq, Wk, Wv, Wo, xb, WqkvT, WoT);
    k_gemm_qkv <<<dim3(1536),   dim3(256), 0, stream>>>(xb, WqkvT, bq, bk, bv, Qb, Kb, VTb);
    k_attn     <<<dim3(8, 64),  dim3(256), 0, stream>>>(Qb, Kb, VTb, A2);
    k_gemm_out <<<dim3(8, 64),  dim3(256), 0, stream>>>(A2, WoT, bo, out);
}